// Round 3
// baseline (780.734 us; speedup 1.0000x reference)
//
#include <hip/hip_runtime.h>
#include <hip/hip_bf16.h>

// GAT: N=100000 nodes, E=1.6M edges, IN=7, H=2 heads, C=64, NC=4.
// Pipeline: CSR build (hist/scan/scatter) -> feat1(+es/ed) -> aggr1 ->
//           esd2 -> gemm2 -> aggr2 -> classifier.

#define LRELU_SLOPE 0.2f

__device__ __forceinline__ float wave_red_max(float v) {
#pragma unroll
    for (int o = 32; o > 0; o >>= 1) v = fmaxf(v, __shfl_xor(v, o));
    return v;
}
__device__ __forceinline__ float wave_red_sum(float v) {
#pragma unroll
    for (int o = 32; o > 0; o >>= 1) v += __shfl_xor(v, o);
    return v;
}
__device__ __forceinline__ float lrelu(float v) { return v > 0.f ? v : LRELU_SLOPE * v; }

// ---- CSR build ----
__global__ void k_hist(const int* __restrict__ dstA, int* __restrict__ cnt, int E) {
    int i = blockIdx.x * 256 + threadIdx.x;
    if (i < E) atomicAdd(&cnt[dstA[i]], 1);
}

__global__ void k_scan1(const int* __restrict__ cnt, int* __restrict__ rs,
                        int* __restrict__ part, int n) {
    __shared__ int sm[256];
    int t = threadIdx.x;
    int i = blockIdx.x * 256 + t;
    int v = (i < n) ? cnt[i] : 0;
    sm[t] = v;
    __syncthreads();
#pragma unroll
    for (int off = 1; off < 256; off <<= 1) {
        int x = (t >= off) ? sm[t - off] : 0;
        __syncthreads();
        sm[t] += x;
        __syncthreads();
    }
    if (i < n) rs[i] = sm[t] - v;          // exclusive within block
    if (t == 255) part[blockIdx.x] = sm[255];
}

__global__ void k_scan2(int* part, int np) {  // np <= 512
    __shared__ int sm[512];
    int t = threadIdx.x;
    int v = (t < np) ? part[t] : 0;
    sm[t] = v;
    __syncthreads();
#pragma unroll
    for (int off = 1; off < 512; off <<= 1) {
        int x = (t >= off) ? sm[t - off] : 0;
        __syncthreads();
        sm[t] += x;
        __syncthreads();
    }
    if (t < np) part[t] = sm[t] - v;       // exclusive across blocks
}

__global__ void k_scan3(int* rs, const int* __restrict__ part, int n, int total) {
    int i = blockIdx.x * 256 + threadIdx.x;
    if (i < n) rs[i] += part[blockIdx.x];
    if (i == 0) rs[n] = total;
}

__global__ void k_scatter(const int* __restrict__ srcA, const int* __restrict__ dstA,
                          const int* __restrict__ rs, int* __restrict__ cur,
                          int* __restrict__ ssrc, int E) {
    int i = blockIdx.x * 256 + threadIdx.x;
    if (i < E) {
        int d = dstA[i];
        int p = atomicAdd(&cur[d], 1);
        ssrc[rs[d] + p] = srcA[i];
    }
}

// ---- precompute ws/wd = W @ a  (so es = x @ ws) ----
__global__ void k_prep(const float* __restrict__ W1, const float* __restrict__ as1,
                       const float* __restrict__ ad1, const float* __restrict__ W2,
                       const float* __restrict__ as2, const float* __restrict__ ad2,
                       float* __restrict__ ws1, float* __restrict__ wd1,
                       float* __restrict__ ws2, float* __restrict__ wd2) {
    int t = threadIdx.x;  // 256 threads: t = k*2+h for W2 (k<128, h<2)
    int k = t >> 1, h = t & 1;
    float s = 0.f, d = 0.f;
    for (int cc = 0; cc < 64; cc++) {
        float w = W2[k * 128 + h * 64 + cc];
        s += w * as2[h * 64 + cc];
        d += w * ad2[h * 64 + cc];
    }
    ws2[t] = s;
    wd2[t] = d;
    if (t < 14) {  // t = k*2+h for W1 (k<7, h<2)
        int kk = t >> 1, hh = t & 1;
        float s1 = 0.f, d1 = 0.f;
        for (int cc = 0; cc < 64; cc++) {
            float w = W1[kk * 128 + hh * 64 + cc];
            s1 += w * as1[hh * 64 + cc];
            d1 += w * ad1[hh * 64 + cc];
        }
        ws1[t] = s1;
        wd1[t] = d1;
    }
}

// ---- layer1 features: h1 = x@W1 (raw), es1/ed1 = x@ws1 / x@wd1 ----
__global__ void k_feat1(const float* __restrict__ x, const float* __restrict__ W1,
                        const float* __restrict__ ws1, const float* __restrict__ wd1,
                        float* __restrict__ h1, float* __restrict__ es1,
                        float* __restrict__ ed1, int n) {
    int node = blockIdx.x;
    int c = threadIdx.x;  // 0..127
    float xv[7];
#pragma unroll
    for (int k = 0; k < 7; k++) xv[k] = x[node * 7 + k];
    float acc = 0.f;
#pragma unroll
    for (int k = 0; k < 7; k++) acc += xv[k] * W1[k * 128 + c];
    h1[node * 128 + c] = acc;
    if (c < 2) {
        float s = 0.f;
#pragma unroll
        for (int k = 0; k < 7; k++) s += xv[k] * ws1[k * 2 + c];
        es1[node * 2 + c] = s;
    } else if (c < 4) {
        int h = c - 2;
        float s = 0.f;
#pragma unroll
        for (int k = 0; k < 7; k++) s += xv[k] * wd1[k * 2 + h];
        ed1[node * 2 + h] = s;
    }
}

// ---- es2/ed2 from out1 ----
__global__ void k_esd2(const float* __restrict__ out1, const float* __restrict__ ws2,
                       const float* __restrict__ wd2, float* __restrict__ es2,
                       float* __restrict__ ed2, int n) {
    int wid = threadIdx.x >> 6, lane = threadIdx.x & 63;
    int node = blockIdx.x * 4 + wid;
    if (node >= n) return;
    float v0 = out1[node * 128 + lane];
    float v1 = out1[node * 128 + 64 + lane];
    float s0 = v0 * ws2[lane * 2 + 0] + v1 * ws2[(lane + 64) * 2 + 0];
    float s1 = v0 * ws2[lane * 2 + 1] + v1 * ws2[(lane + 64) * 2 + 1];
    float d0 = v0 * wd2[lane * 2 + 0] + v1 * wd2[(lane + 64) * 2 + 0];
    float d1 = v0 * wd2[lane * 2 + 1] + v1 * wd2[(lane + 64) * 2 + 1];
    s0 = wave_red_sum(s0);
    s1 = wave_red_sum(s1);
    d0 = wave_red_sum(d0);
    d1 = wave_red_sum(d1);
    if (lane == 0) {
        es2[node * 2 + 0] = s0;
        es2[node * 2 + 1] = s1;
        ed2[node * 2 + 0] = d0;
        ed2[node * 2 + 1] = d1;
    }
}

// ---- GAT aggregation: one wave per dst node ----
// LAYER==1: concat heads, +b1, relu -> out[n][128]
// LAYER==2: mean heads,  +b2       -> out[n][64]
template <int LAYER>
__global__ void k_aggr(const float* __restrict__ h, const float* __restrict__ es,
                       const float* __restrict__ ed, const int* __restrict__ rs,
                       const int* __restrict__ ssrc, const float* __restrict__ bias,
                       float* __restrict__ out, int n) {
    int wid = threadIdx.x >> 6, lane = threadIdx.x & 63;
    int node = blockIdx.x * 4 + wid;
    if (node >= n) return;
    int beg = rs[node], end = rs[node + 1];
    int deg = end - beg;
    float edv0 = ed[node * 2 + 0], edv1 = ed[node * 2 + 1];
    float e0s = lrelu(es[node * 2 + 0] + edv0);  // implicit self-loop
    float e1s = lrelu(es[node * 2 + 1] + edv1);
    float m0 = e0s, s0 = 1.f, m1 = e1s, s1 = 1.f;
    // phase 1: online softmax stats over incoming edges
    for (int c0 = 0; c0 < deg; c0 += 64) {
        int i = c0 + lane;
        bool val = i < deg;
        int sv = val ? ssrc[beg + i] : 0;
        float e0 = val ? lrelu(es[sv * 2 + 0] + edv0) : -3.0e38f;
        float e1 = val ? lrelu(es[sv * 2 + 1] + edv1) : -3.0e38f;
        float nm0 = fmaxf(m0, wave_red_max(e0));
        float nm1 = fmaxf(m1, wave_red_max(e1));
        float p0 = val ? __expf(e0 - nm0) : 0.f;
        float p1 = val ? __expf(e1 - nm1) : 0.f;
        s0 = s0 * __expf(m0 - nm0) + wave_red_sum(p0);
        s1 = s1 * __expf(m1 - nm1) + wave_red_sum(p1);
        m0 = nm0;
        m1 = nm1;
    }
    float inv0 = 1.f / s0, inv1 = 1.f / s1;
    int head = lane >> 5;
    // phase 2: aggregate (self first)
    float aself = head ? __expf(e1s - m1) * inv1 : __expf(e0s - m0) * inv0;
    float2 hv = *(const float2*)&h[node * 128 + lane * 2];
    float accx = hv.x * aself, accy = hv.y * aself;
    for (int c0 = 0; c0 < deg; c0 += 64) {
        int i = c0 + lane;
        bool val = i < deg;
        int sv = val ? ssrc[beg + i] : 0;
        float a0 = 0.f, a1 = 0.f;
        if (val) {
            float e0 = lrelu(es[sv * 2 + 0] + edv0);
            float e1 = lrelu(es[sv * 2 + 1] + edv1);
            a0 = __expf(e0 - m0) * inv0;
            a1 = __expf(e1 - m1) * inv1;
        }
        int cnt = min(64, deg - c0);
        for (int j = 0; j < cnt; j++) {
            int sj = __shfl(sv, j);
            float b0 = __shfl(a0, j);
            float b1 = __shfl(a1, j);
            float a = head ? b1 : b0;
            float2 hh = *(const float2*)&h[sj * 128 + lane * 2];
            accx += hh.x * a;
            accy += hh.y * a;
        }
    }
    if (LAYER == 1) {
        float2 bv = *(const float2*)&bias[lane * 2];
        float2 o;
        o.x = fmaxf(accx + bv.x, 0.f);
        o.y = fmaxf(accy + bv.y, 0.f);
        *(float2*)&out[node * 128 + lane * 2] = o;
    } else {
        float px = __shfl_xor(accx, 32);
        float py = __shfl_xor(accy, 32);
        if (lane < 32) {
            float2 bv = *(const float2*)&bias[lane * 2];
            float2 o;
            o.x = 0.5f * (accx + px) + bv.x;
            o.y = 0.5f * (accy + py) + bv.y;
            *(float2*)&out[node * 64 + lane * 2] = o;
        }
    }
}

// ---- layer2 GEMM: h2[M,128] = out1[M,128] @ W2[128,128] (fp32 vector ALU) ----
__global__ void k_gemm2(const float* __restrict__ A, const float* __restrict__ B,
                        float* __restrict__ C, int M) {
    __shared__ float As[32][65];    // [k][m]
    __shared__ float Bs[32][132];   // [k][n], float4-aligned rows
    int bm = blockIdx.x * 64;
    int t = threadIdx.x;
    int tx = t & 31;   // n0 = tx*4
    int ty = t >> 5;   // m0 = ty*8
    float acc[8][4];
#pragma unroll
    for (int i = 0; i < 8; i++)
#pragma unroll
        for (int j = 0; j < 4; j++) acc[i][j] = 0.f;

    for (int k0 = 0; k0 < 128; k0 += 32) {
        int lk = t & 31, lm = t >> 5;
#pragma unroll
        for (int p = 0; p < 8; p++) {
            int m = lm + p * 8;
            int row = bm + m;
            As[lk][m] = (row < M) ? A[row * 128 + k0 + lk] : 0.f;
        }
        int bn = t & 127, bk = t >> 7;
#pragma unroll
        for (int p = 0; p < 16; p++) {
            Bs[bk + p * 2][bn] = B[(k0 + bk + p * 2) * 128 + bn];
        }
        __syncthreads();
#pragma unroll
        for (int k = 0; k < 32; k++) {
            float a[8];
#pragma unroll
            for (int i = 0; i < 8; i++) a[i] = As[k][ty * 8 + i];
            float4 bv = *(const float4*)&Bs[k][tx * 4];
            float b[4] = {bv.x, bv.y, bv.z, bv.w};
#pragma unroll
            for (int i = 0; i < 8; i++)
#pragma unroll
                for (int j = 0; j < 4; j++) acc[i][j] += a[i] * b[j];
        }
        __syncthreads();
    }
#pragma unroll
    for (int i = 0; i < 8; i++) {
        int row = bm + ty * 8 + i;
        if (row < M) {
            float4 v = {acc[i][0], acc[i][1], acc[i][2], acc[i][3]};
            *(float4*)&C[row * 128 + tx * 4] = v;
        }
    }
}

// ---- fused classifier: out = relu(out2@Wc1+bc1)@Wc2+bc2 ----
__global__ void k_cls(const float* __restrict__ out2, const float* __restrict__ Wc1,
                      const float* __restrict__ bc1, const float* __restrict__ Wc2,
                      const float* __restrict__ bc2, float* __restrict__ out, int n) {
    int wid = threadIdx.x >> 6, lane = threadIdx.x & 63;
    int node = blockIdx.x * 4 + wid;
    if (node >= n) return;
    float acc = bc1[lane];
#pragma unroll 8
    for (int k = 0; k < 64; k++) acc += out2[node * 64 + k] * Wc1[k * 64 + lane];
    acc = fmaxf(acc, 0.f);
    float p0 = acc * Wc2[lane * 4 + 0];
    float p1 = acc * Wc2[lane * 4 + 1];
    float p2 = acc * Wc2[lane * 4 + 2];
    float p3 = acc * Wc2[lane * 4 + 3];
    p0 = wave_red_sum(p0);
    p1 = wave_red_sum(p1);
    p2 = wave_red_sum(p2);
    p3 = wave_red_sum(p3);
    if (lane == 0) {
        float4 o = {p0 + bc2[0], p1 + bc2[1], p2 + bc2[2], p3 + bc2[3]};
        *(float4*)&out[node * 4] = o;
    }
}

extern "C" void kernel_launch(void* const* d_in, const int* in_sizes, int n_in,
                              void* d_out, int out_size, void* d_ws, size_t ws_size,
                              hipStream_t stream) {
    const float* x   = (const float*)d_in[0];
    const int*   ei  = (const int*)d_in[1];
    const float* W1  = (const float*)d_in[2];
    const float* as1 = (const float*)d_in[3];
    const float* ad1 = (const float*)d_in[4];
    const float* b1  = (const float*)d_in[5];
    const float* W2  = (const float*)d_in[6];
    const float* as2 = (const float*)d_in[7];
    const float* ad2 = (const float*)d_in[8];
    const float* b2  = (const float*)d_in[9];
    const float* Wc1 = (const float*)d_in[10];
    const float* bc1 = (const float*)d_in[11];
    const float* Wc2 = (const float*)d_in[12];
    const float* bc2 = (const float*)d_in[13];
    float* out = (float*)d_out;

    int n = in_sizes[0] / 7;
    int E = in_sizes[1] / 2;
    const int* srcA = ei;
    const int* dstA = ei + E;

    char* ws = (char*)d_ws;
    size_t off = 0;
    auto alloc = [&](size_t bytes) -> char* {
        char* p = ws + off;
        off += (bytes + 255) & ~(size_t)255;
        return p;
    };
    float* bufH = (float*)alloc((size_t)n * 128 * 4);  // h1, then h2
    float* bufO = (float*)alloc((size_t)n * 128 * 4);  // out1, then out2
    float* es1  = (float*)alloc((size_t)n * 2 * 4);
    float* ed1  = (float*)alloc((size_t)n * 2 * 4);
    float* es2  = (float*)alloc((size_t)n * 2 * 4);
    float* ed2  = (float*)alloc((size_t)n * 2 * 4);
    float* ws1  = (float*)alloc(64);
    float* wd1  = (float*)alloc(64);
    float* ws2v = (float*)alloc(256 * 4);
    float* wd2v = (float*)alloc(256 * 4);
    int* rs   = (int*)alloc((size_t)(n + 1) * 4);
    int* cnt  = (int*)alloc((size_t)n * 4);
    int* part = (int*)alloc(512 * 4);
    int* ssrc = (int*)alloc((size_t)E * 4);

    int eb = (E + 255) / 256;
    int nb = (n + 255) / 256;  // 391 for n=100000 (<512, fits k_scan2)

    hipMemsetAsync(cnt, 0, (size_t)n * 4, stream);
    k_hist<<<eb, 256, 0, stream>>>(dstA, cnt, E);
    k_scan1<<<nb, 256, 0, stream>>>(cnt, rs, part, n);
    k_scan2<<<1, 512, 0, stream>>>(part, nb);
    k_scan3<<<nb, 256, 0, stream>>>(rs, part, n, E);
    hipMemsetAsync(cnt, 0, (size_t)n * 4, stream);
    k_scatter<<<eb, 256, 0, stream>>>(srcA, dstA, rs, cnt, ssrc, E);

    k_prep<<<1, 256, 0, stream>>>(W1, as1, ad1, W2, as2, ad2, ws1, wd1, ws2v, wd2v);
    k_feat1<<<n, 128, 0, stream>>>(x, W1, ws1, wd1, bufH, es1, ed1, n);
    k_aggr<1><<<(n + 3) / 4, 256, 0, stream>>>(bufH, es1, ed1, rs, ssrc, b1, bufO, n);
    k_esd2<<<(n + 3) / 4, 256, 0, stream>>>(bufO, ws2v, wd2v, es2, ed2, n);
    k_gemm2<<<(n + 63) / 64, 256, 0, stream>>>(bufO, W2, bufH, n);
    k_aggr<2><<<(n + 3) / 4, 256, 0, stream>>>(bufH, es2, ed2, rs, ssrc, b2, bufO, n);
    k_cls<<<(n + 3) / 4, 256, 0, stream>>>(bufO, Wc1, bc1, Wc2, bc2, out, n);
}

// Round 7
// 654.437 us; speedup vs baseline: 1.1930x; 1.1930x over previous
//
#include <hip/hip_runtime.h>
#include <hip/hip_bf16.h>

// GAT: N=100000 nodes, E=1.6M edges, IN=7, H=2 heads, C=64, NC=4.
// Pipeline: CSR build -> feat1(+es/ed) -> aggr1(+es2/ed2 fused) -> gemm2 ->
//           aggr2(+classifier fused).
// R3: aggr latency-bound (VGPR=16, VALUBusy 36%, HBM 40%) -> deg<=64 fast path.
// R6 FIX: divergent-ternary __shfl (ds_bpermute reads from exec-masked lanes
// are UNDEFINED) -> always shuffle both heads' alphas unconditionally, then
// select per-lane (the R3-proven-safe pattern).

#define LRELU_SLOPE 0.2f

__device__ __forceinline__ float wave_red_max(float v) {
#pragma unroll
    for (int o = 32; o > 0; o >>= 1) v = fmaxf(v, __shfl_xor(v, o));
    return v;
}
__device__ __forceinline__ float wave_red_sum(float v) {
#pragma unroll
    for (int o = 32; o > 0; o >>= 1) v += __shfl_xor(v, o);
    return v;
}
__device__ __forceinline__ float lrelu(float v) { return v > 0.f ? v : LRELU_SLOPE * v; }

// ---- CSR build ----
__global__ void k_hist(const int* __restrict__ dstA, int* __restrict__ cnt, int E) {
    int i = blockIdx.x * 256 + threadIdx.x;
    if (i < E) atomicAdd(&cnt[dstA[i]], 1);
}

__global__ void k_scan1(const int* __restrict__ cnt, int* __restrict__ rs,
                        int* __restrict__ part, int n) {
    __shared__ int sm[256];
    int t = threadIdx.x;
    int i = blockIdx.x * 256 + t;
    int v = (i < n) ? cnt[i] : 0;
    sm[t] = v;
    __syncthreads();
#pragma unroll
    for (int off = 1; off < 256; off <<= 1) {
        int x = (t >= off) ? sm[t - off] : 0;
        __syncthreads();
        sm[t] += x;
        __syncthreads();
    }
    if (i < n) rs[i] = sm[t] - v;
    if (t == 255) part[blockIdx.x] = sm[255];
}

__global__ void k_scan2(int* part, int np) {  // np <= 512
    __shared__ int sm[512];
    int t = threadIdx.x;
    int v = (t < np) ? part[t] : 0;
    sm[t] = v;
    __syncthreads();
#pragma unroll
    for (int off = 1; off < 512; off <<= 1) {
        int x = (t >= off) ? sm[t - off] : 0;
        __syncthreads();
        sm[t] += x;
        __syncthreads();
    }
    if (t < np) part[t] = sm[t] - v;
}

__global__ void k_scan3(int* rs, const int* __restrict__ part, int n, int total) {
    int i = blockIdx.x * 256 + threadIdx.x;
    if (i < n) rs[i] += part[blockIdx.x];
    if (i == 0) rs[n] = total;
}

__global__ void k_scatter(const int* __restrict__ srcA, const int* __restrict__ dstA,
                          const int* __restrict__ rs, int* __restrict__ cur,
                          int* __restrict__ ssrc, int E) {
    int i = blockIdx.x * 256 + threadIdx.x;
    if (i < E) {
        int d = dstA[i];
        int p = atomicAdd(&cur[d], 1);
        ssrc[rs[d] + p] = srcA[i];
    }
}

// ---- precompute ws/wd = W @ a ----
__global__ void k_prep(const float* __restrict__ W1, const float* __restrict__ as1,
                       const float* __restrict__ ad1, const float* __restrict__ W2,
                       const float* __restrict__ as2, const float* __restrict__ ad2,
                       float* __restrict__ ws1, float* __restrict__ wd1,
                       float* __restrict__ ws2, float* __restrict__ wd2) {
    int t = threadIdx.x;  // t = k*2+h for W2 (k<128, h<2)
    int k = t >> 1, h = t & 1;
    float s = 0.f, d = 0.f;
    for (int cc = 0; cc < 64; cc++) {
        float w = W2[k * 128 + h * 64 + cc];
        s += w * as2[h * 64 + cc];
        d += w * ad2[h * 64 + cc];
    }
    ws2[t] = s;
    wd2[t] = d;
    if (t < 14) {
        int kk = t >> 1, hh = t & 1;
        float s1 = 0.f, d1 = 0.f;
        for (int cc = 0; cc < 64; cc++) {
            float w = W1[kk * 128 + hh * 64 + cc];
            s1 += w * as1[hh * 64 + cc];
            d1 += w * ad1[hh * 64 + cc];
        }
        ws1[t] = s1;
        wd1[t] = d1;
    }
}

// ---- layer1 features ----
__global__ void k_feat1(const float* __restrict__ x, const float* __restrict__ W1,
                        const float* __restrict__ ws1, const float* __restrict__ wd1,
                        float* __restrict__ h1, float* __restrict__ es1,
                        float* __restrict__ ed1, int n) {
    int node = blockIdx.x;
    int c = threadIdx.x;  // 0..127
    float xv[7];
#pragma unroll
    for (int k = 0; k < 7; k++) xv[k] = x[node * 7 + k];
    float acc = 0.f;
#pragma unroll
    for (int k = 0; k < 7; k++) acc += xv[k] * W1[k * 128 + c];
    h1[node * 128 + c] = acc;
    if (c < 2) {
        float s = 0.f;
#pragma unroll
        for (int k = 0; k < 7; k++) s += xv[k] * ws1[k * 2 + c];
        es1[node * 2 + c] = s;
    } else if (c < 4) {
        int h = c - 2;
        float s = 0.f;
#pragma unroll
        for (int k = 0; k < 7; k++) s += xv[k] * wd1[k * 2 + h];
        ed1[node * 2 + h] = s;
    }
}

// ---- GAT aggregation, one wave per dst node ----
// LAYER==1: concat+b1+relu -> out[n][128]; fused es2/ed2 epilogue.
// LAYER==2: mean+b2 -> fused classifier -> out[n][4] (final output).
template <int LAYER>
__global__ void k_aggr(const float* __restrict__ h, const float* __restrict__ es,
                       const float* __restrict__ ed, const int* __restrict__ rs,
                       const int* __restrict__ ssrc, const float* __restrict__ bias,
                       float* __restrict__ out, const float* __restrict__ ws2,
                       const float* __restrict__ wd2, float* __restrict__ es2,
                       float* __restrict__ ed2, const float* __restrict__ Wc1,
                       const float* __restrict__ bc1, const float* __restrict__ Wc2,
                       const float* __restrict__ bc2, int n) {
    int wid = threadIdx.x >> 6, lane = threadIdx.x & 63;
    int node = blockIdx.x * 4 + wid;
    if (node >= n) return;
    int beg = rs[node], deg = rs[node + 1] - beg;
    float2 edv = *(const float2*)&ed[node * 2];
    float2 esn = *(const float2*)&es[node * 2];
    float e0s = lrelu(esn.x + edv.x);  // implicit self-loop score
    float e1s = lrelu(esn.y + edv.y);
    int head = lane >> 5;
    float accx, accy;

    if (deg <= 64) {
        // ---- fast path: edge state register-resident ----
        bool valid = lane < deg;
        int sv = valid ? ssrc[beg + lane] : 0;
        float2 ev;
        ev.x = 0.f; ev.y = 0.f;
        if (valid) ev = *(const float2*)&es[sv * 2];
        float e0 = valid ? lrelu(ev.x + edv.x) : -3.0e38f;
        float e1 = valid ? lrelu(ev.y + edv.y) : -3.0e38f;
        float m0 = fmaxf(wave_red_max(e0), e0s);
        float m1 = fmaxf(wave_red_max(e1), e1s);
        float p0 = valid ? __expf(e0 - m0) : 0.f;
        float p1 = valid ? __expf(e1 - m1) : 0.f;
        float exs0 = __expf(e0s - m0), exs1 = __expf(e1s - m1);
        float inv0 = 1.f / (wave_red_sum(p0) + exs0);
        float inv1 = 1.f / (wave_red_sum(p1) + exs1);
        float a0 = p0 * inv0, a1 = p1 * inv1;
        float aself = head ? exs1 * inv1 : exs0 * inv0;
        float2 hv = *(const float2*)&h[(size_t)node * 128 + lane * 2];
        float ax0 = hv.x * aself, ay0 = hv.y * aself;
        float ax1 = 0.f, ay1 = 0.f;
        int j = 0;
        for (; j + 4 <= deg; j += 4) {  // 4 gathers in flight, 2 acc pairs
            // shuffle BOTH heads' alphas unconditionally (all 64 lanes active),
            // THEN select per-lane — divergent shfl is undefined (R6 fix).
            int sj0 = __shfl(sv, j), sj1 = __shfl(sv, j + 1);
            int sj2 = __shfl(sv, j + 2), sj3 = __shfl(sv, j + 3);
            float b00 = __shfl(a0, j),     b10 = __shfl(a1, j);
            float b01 = __shfl(a0, j + 1), b11 = __shfl(a1, j + 1);
            float b02 = __shfl(a0, j + 2), b12 = __shfl(a1, j + 2);
            float b03 = __shfl(a0, j + 3), b13 = __shfl(a1, j + 3);
            float aa0 = head ? b10 : b00;
            float aa1 = head ? b11 : b01;
            float aa2 = head ? b12 : b02;
            float aa3 = head ? b13 : b03;
            float2 h0 = *(const float2*)&h[(size_t)sj0 * 128 + lane * 2];
            float2 h1v = *(const float2*)&h[(size_t)sj1 * 128 + lane * 2];
            float2 h2v = *(const float2*)&h[(size_t)sj2 * 128 + lane * 2];
            float2 h3v = *(const float2*)&h[(size_t)sj3 * 128 + lane * 2];
            ax0 += h0.x * aa0; ay0 += h0.y * aa0;
            ax1 += h1v.x * aa1; ay1 += h1v.y * aa1;
            ax0 += h2v.x * aa2; ay0 += h2v.y * aa2;
            ax1 += h3v.x * aa3; ay1 += h3v.y * aa3;
        }
        for (; j < deg; j++) {
            int sj = __shfl(sv, j);
            float b0 = __shfl(a0, j), b1 = __shfl(a1, j);
            float aa = head ? b1 : b0;
            float2 hh = *(const float2*)&h[(size_t)sj * 128 + lane * 2];
            ax0 += hh.x * aa; ay0 += hh.y * aa;
        }
        accx = ax0 + ax1; accy = ay0 + ay1;
    } else {
        // ---- generic chunked path (deg > 64; vanishingly rare) ----
        float m0 = e0s, s0 = 1.f, m1 = e1s, s1 = 1.f;
        for (int c0 = 0; c0 < deg; c0 += 64) {
            int i = c0 + lane;
            bool val = i < deg;
            int sv = val ? ssrc[beg + i] : 0;
            float e0 = val ? lrelu(es[sv * 2 + 0] + edv.x) : -3.0e38f;
            float e1 = val ? lrelu(es[sv * 2 + 1] + edv.y) : -3.0e38f;
            float nm0 = fmaxf(m0, wave_red_max(e0));
            float nm1 = fmaxf(m1, wave_red_max(e1));
            float p0 = val ? __expf(e0 - nm0) : 0.f;
            float p1 = val ? __expf(e1 - nm1) : 0.f;
            s0 = s0 * __expf(m0 - nm0) + wave_red_sum(p0);
            s1 = s1 * __expf(m1 - nm1) + wave_red_sum(p1);
            m0 = nm0; m1 = nm1;
        }
        float inv0 = 1.f / s0, inv1 = 1.f / s1;
        float aself = head ? __expf(e1s - m1) * inv1 : __expf(e0s - m0) * inv0;
        float2 hv = *(const float2*)&h[(size_t)node * 128 + lane * 2];
        accx = hv.x * aself; accy = hv.y * aself;
        for (int c0 = 0; c0 < deg; c0 += 64) {
            int i = c0 + lane;
            bool val = i < deg;
            int sv = val ? ssrc[beg + i] : 0;
            float a0 = 0.f, a1 = 0.f;
            if (val) {
                float e0 = lrelu(es[sv * 2 + 0] + edv.x);
                float e1 = lrelu(es[sv * 2 + 1] + edv.y);
                a0 = __expf(e0 - m0) * inv0;
                a1 = __expf(e1 - m1) * inv1;
            }
            int cnt = min(64, deg - c0);
            for (int j = 0; j < cnt; j++) {
                int sj = __shfl(sv, j);
                float b0 = __shfl(a0, j);
                float b1 = __shfl(a1, j);
                float a = head ? b1 : b0;
                float2 hh = *(const float2*)&h[(size_t)sj * 128 + lane * 2];
                accx += hh.x * a; accy += hh.y * a;
            }
        }
    }

    if (LAYER == 1) {
        float2 bv = *(const float2*)&bias[lane * 2];
        float ox = fmaxf(accx + bv.x, 0.f);
        float oy = fmaxf(accy + bv.y, 0.f);
        float2 o; o.x = ox; o.y = oy;
        *(float2*)&out[(size_t)node * 128 + lane * 2] = o;
        // fused es2/ed2: channel c0=2*lane, c1=2*lane+1; ws2/wd2 layout [k][h]
        float4 wsv = *(const float4*)&ws2[lane * 4];
        float4 wdv = *(const float4*)&wd2[lane * 4];
        float s0 = ox * wsv.x + oy * wsv.z;
        float s1 = ox * wsv.y + oy * wsv.w;
        float d0 = ox * wdv.x + oy * wdv.z;
        float d1 = ox * wdv.y + oy * wdv.w;
        s0 = wave_red_sum(s0); s1 = wave_red_sum(s1);
        d0 = wave_red_sum(d0); d1 = wave_red_sum(d1);
        if (lane == 0) {
            float2 sv2; sv2.x = s0; sv2.y = s1;
            float2 dv2; dv2.x = d0; dv2.y = d1;
            *(float2*)&es2[node * 2] = sv2;
            *(float2*)&ed2[node * 2] = dv2;
        }
    } else {
        // mean heads (+b2): lane l and l+32 both end up with channel pair 2*(l&31)
        float px = __shfl_xor(accx, 32);
        float py = __shfl_xor(accy, 32);
        int l2 = lane & 31;
        float2 bv = *(const float2*)&bias[l2 * 2];
        float ox = 0.5f * (accx + px) + bv.x;   // channel 2*l2
        float oy = 0.5f * (accy + py) + bv.y;   // channel 2*l2+1
        // fused classifier: y[c]=relu(sum_k o[k]*Wc1[k][c]+bc1[c]); out=y@Wc2+bc2
        float yc0 = bc1[lane], yc1 = 0.f;
#pragma unroll
        for (int q = 0; q < 32; q += 2) {
            float vx0 = __shfl(ox, q), vy0 = __shfl(oy, q);
            float vx1 = __shfl(ox, q + 1), vy1 = __shfl(oy, q + 1);
            yc0 += vx0 * Wc1[(2 * q) * 64 + lane] + vy0 * Wc1[(2 * q + 1) * 64 + lane];
            yc1 += vx1 * Wc1[(2 * q + 2) * 64 + lane] + vy1 * Wc1[(2 * q + 3) * 64 + lane];
        }
        float y = fmaxf(yc0 + yc1, 0.f);
        float4 w2v = *(const float4*)&Wc2[lane * 4];
        float p0 = y * w2v.x, p1 = y * w2v.y, p2 = y * w2v.z, p3 = y * w2v.w;
        p0 = wave_red_sum(p0); p1 = wave_red_sum(p1);
        p2 = wave_red_sum(p2); p3 = wave_red_sum(p3);
        if (lane == 0) {
            float4 o; o.x = p0 + bc2[0]; o.y = p1 + bc2[1];
            o.z = p2 + bc2[2]; o.w = p3 + bc2[3];
            *(float4*)&out[(size_t)node * 4] = o;
        }
    }
}

// ---- layer2 GEMM: h2[M,128] = out1[M,128] @ W2[128,128] ----
__global__ void k_gemm2(const float* __restrict__ A, const float* __restrict__ B,
                        float* __restrict__ C, int M) {
    __shared__ float As[32][65];
    __shared__ float Bs[32][132];
    int bm = blockIdx.x * 64;
    int t = threadIdx.x;
    int tx = t & 31;
    int ty = t >> 5;
    float acc[8][4];
#pragma unroll
    for (int i = 0; i < 8; i++)
#pragma unroll
        for (int j = 0; j < 4; j++) acc[i][j] = 0.f;

    for (int k0 = 0; k0 < 128; k0 += 32) {
        int lk = t & 31, lm = t >> 5;
#pragma unroll
        for (int p = 0; p < 8; p++) {
            int m = lm + p * 8;
            int row = bm + m;
            As[lk][m] = (row < M) ? A[row * 128 + k0 + lk] : 0.f;
        }
        int bn = t & 127, bk = t >> 7;
#pragma unroll
        for (int p = 0; p < 16; p++) {
            Bs[bk + p * 2][bn] = B[(k0 + bk + p * 2) * 128 + bn];
        }
        __syncthreads();
#pragma unroll
        for (int k = 0; k < 32; k++) {
            float a[8];
#pragma unroll
            for (int i = 0; i < 8; i++) a[i] = As[k][ty * 8 + i];
            float4 bv = *(const float4*)&Bs[k][tx * 4];
            float b[4] = {bv.x, bv.y, bv.z, bv.w};
#pragma unroll
            for (int i = 0; i < 8; i++)
#pragma unroll
                for (int j = 0; j < 4; j++) acc[i][j] += a[i] * b[j];
        }
        __syncthreads();
    }
#pragma unroll
    for (int i = 0; i < 8; i++) {
        int row = bm + ty * 8 + i;
        if (row < M) {
            float4 v = {acc[i][0], acc[i][1], acc[i][2], acc[i][3]};
            *(float4*)&C[row * 128 + tx * 4] = v;
        }
    }
}

extern "C" void kernel_launch(void* const* d_in, const int* in_sizes, int n_in,
                              void* d_out, int out_size, void* d_ws, size_t ws_size,
                              hipStream_t stream) {
    const float* x   = (const float*)d_in[0];
    const int*   ei  = (const int*)d_in[1];
    const float* W1  = (const float*)d_in[2];
    const float* as1 = (const float*)d_in[3];
    const float* ad1 = (const float*)d_in[4];
    const float* b1  = (const float*)d_in[5];
    const float* W2  = (const float*)d_in[6];
    const float* as2 = (const float*)d_in[7];
    const float* ad2 = (const float*)d_in[8];
    const float* b2  = (const float*)d_in[9];
    const float* Wc1 = (const float*)d_in[10];
    const float* bc1 = (const float*)d_in[11];
    const float* Wc2 = (const float*)d_in[12];
    const float* bc2 = (const float*)d_in[13];
    float* out = (float*)d_out;

    int n = in_sizes[0] / 7;
    int E = in_sizes[1] / 2;
    const int* srcA = ei;
    const int* dstA = ei + E;

    char* ws = (char*)d_ws;
    size_t off = 0;
    auto alloc = [&](size_t bytes) -> char* {
        char* p = ws + off;
        off += (bytes + 255) & ~(size_t)255;
        return p;
    };
    float* bufH = (float*)alloc((size_t)n * 128 * 4);  // h1, then h2
    float* bufO = (float*)alloc((size_t)n * 128 * 4);  // out1
    float* es1  = (float*)alloc((size_t)n * 2 * 4);
    float* ed1  = (float*)alloc((size_t)n * 2 * 4);
    float* es2  = (float*)alloc((size_t)n * 2 * 4);
    float* ed2  = (float*)alloc((size_t)n * 2 * 4);
    float* ws1  = (float*)alloc(64);
    float* wd1  = (float*)alloc(64);
    float* ws2v = (float*)alloc(256 * 4);
    float* wd2v = (float*)alloc(256 * 4);
    int* rs   = (int*)alloc((size_t)(n + 1) * 4);
    int* cnt  = (int*)alloc((size_t)n * 4);
    int* part = (int*)alloc(512 * 4);
    int* ssrc = (int*)alloc((size_t)E * 4);

    int eb = (E + 255) / 256;
    int nb = (n + 255) / 256;  // 391 (<512, fits k_scan2)

    hipMemsetAsync(cnt, 0, (size_t)n * 4, stream);
    k_hist<<<eb, 256, 0, stream>>>(dstA, cnt, E);
    k_scan1<<<nb, 256, 0, stream>>>(cnt, rs, part, n);
    k_scan2<<<1, 512, 0, stream>>>(part, nb);
    k_scan3<<<nb, 256, 0, stream>>>(rs, part, n, E);
    hipMemsetAsync(cnt, 0, (size_t)n * 4, stream);
    k_scatter<<<eb, 256, 0, stream>>>(srcA, dstA, rs, cnt, ssrc, E);

    k_prep<<<1, 256, 0, stream>>>(W1, as1, ad1, W2, as2, ad2, ws1, wd1, ws2v, wd2v);
    k_feat1<<<n, 128, 0, stream>>>(x, W1, ws1, wd1, bufH, es1, ed1, n);
    k_aggr<1><<<(n + 3) / 4, 256, 0, stream>>>(bufH, es1, ed1, rs, ssrc, b1, bufO,
                                               ws2v, wd2v, es2, ed2,
                                               nullptr, nullptr, nullptr, nullptr, n);
    k_gemm2<<<(n + 63) / 64, 256, 0, stream>>>(bufO, W2, bufH, n);
    k_aggr<2><<<(n + 3) / 4, 256, 0, stream>>>(bufH, es2, ed2, rs, ssrc, b2, out,
                                               nullptr, nullptr, nullptr, nullptr,
                                               Wc1, bc1, Wc2, bc2, n);
}

// Round 11
// 623.684 us; speedup vs baseline: 1.2518x; 1.0493x over previous
//
#include <hip/hip_runtime.h>
#include <hip/hip_bf16.h>

// GAT: N=100000 nodes, E=1.6M edges, IN=7, H=2 heads, C=64, NC=4.
// Pipeline: CSR build -> feat1(+es/ed, bf16 h1) -> aggr1(+es2/ed2 fused) ->
//           gemm2(fp32 in, bf16 h2 out) -> aggr2(+classifier fused).
// R3: aggr latency-bound. R6 fix: no divergent shfl. R8: gathers are
// L2-miss-bound (FETCH 439MB vs 51MB buffer; L2=32MB agg) -> store h1/h2 as
// bf16 (halves gather bytes, doubles L2 coverage) + unroll 8 for MLP.

#define LRELU_SLOPE 0.2f

__device__ __forceinline__ float wave_red_max(float v) {
#pragma unroll
    for (int o = 32; o > 0; o >>= 1) v = fmaxf(v, __shfl_xor(v, o));
    return v;
}
__device__ __forceinline__ float wave_red_sum(float v) {
#pragma unroll
    for (int o = 32; o > 0; o >>= 1) v += __shfl_xor(v, o);
    return v;
}
__device__ __forceinline__ float lrelu(float v) { return v > 0.f ? v : LRELU_SLOPE * v; }
__device__ __forceinline__ float bf2f(unsigned short u) {
    return __uint_as_float(((unsigned int)u) << 16);
}
__device__ __forceinline__ unsigned short f2bf(float f) {  // RNE, finite inputs
    unsigned int x = __float_as_uint(f);
    return (unsigned short)((x + 0x7fffu + ((x >> 16) & 1u)) >> 16);
}

// ---- CSR build ----
__global__ void k_hist(const int* __restrict__ dstA, int* __restrict__ cnt, int E) {
    int i = blockIdx.x * 256 + threadIdx.x;
    if (i < E) atomicAdd(&cnt[dstA[i]], 1);
}

__global__ void k_scan1(const int* __restrict__ cnt, int* __restrict__ rs,
                        int* __restrict__ part, int n) {
    __shared__ int sm[256];
    int t = threadIdx.x;
    int i = blockIdx.x * 256 + t;
    int v = (i < n) ? cnt[i] : 0;
    sm[t] = v;
    __syncthreads();
#pragma unroll
    for (int off = 1; off < 256; off <<= 1) {
        int x = (t >= off) ? sm[t - off] : 0;
        __syncthreads();
        sm[t] += x;
        __syncthreads();
    }
    if (i < n) rs[i] = sm[t] - v;
    if (t == 255) part[blockIdx.x] = sm[255];
}

__global__ void k_scan2(int* part, int np) {  // np <= 512
    __shared__ int sm[512];
    int t = threadIdx.x;
    int v = (t < np) ? part[t] : 0;
    sm[t] = v;
    __syncthreads();
#pragma unroll
    for (int off = 1; off < 512; off <<= 1) {
        int x = (t >= off) ? sm[t - off] : 0;
        __syncthreads();
        sm[t] += x;
        __syncthreads();
    }
    if (t < np) part[t] = sm[t] - v;
}

__global__ void k_scan3(int* rs, const int* __restrict__ part, int n, int total) {
    int i = blockIdx.x * 256 + threadIdx.x;
    if (i < n) rs[i] += part[blockIdx.x];
    if (i == 0) rs[n] = total;
}

__global__ void k_scatter(const int* __restrict__ srcA, const int* __restrict__ dstA,
                          const int* __restrict__ rs, int* __restrict__ cur,
                          int* __restrict__ ssrc, int E) {
    int i = blockIdx.x * 256 + threadIdx.x;
    if (i < E) {
        int d = dstA[i];
        int p = atomicAdd(&cur[d], 1);
        ssrc[rs[d] + p] = srcA[i];
    }
}

// ---- precompute ws/wd = W @ a ----
__global__ void k_prep(const float* __restrict__ W1, const float* __restrict__ as1,
                       const float* __restrict__ ad1, const float* __restrict__ W2,
                       const float* __restrict__ as2, const float* __restrict__ ad2,
                       float* __restrict__ ws1, float* __restrict__ wd1,
                       float* __restrict__ ws2, float* __restrict__ wd2) {
    int t = threadIdx.x;  // t = k*2+h for W2 (k<128, h<2)
    int k = t >> 1, h = t & 1;
    float s = 0.f, d = 0.f;
    for (int cc = 0; cc < 64; cc++) {
        float w = W2[k * 128 + h * 64 + cc];
        s += w * as2[h * 64 + cc];
        d += w * ad2[h * 64 + cc];
    }
    ws2[t] = s;
    wd2[t] = d;
    if (t < 14) {
        int kk = t >> 1, hh = t & 1;
        float s1 = 0.f, d1 = 0.f;
        for (int cc = 0; cc < 64; cc++) {
            float w = W1[kk * 128 + hh * 64 + cc];
            s1 += w * as1[hh * 64 + cc];
            d1 += w * ad1[hh * 64 + cc];
        }
        ws1[t] = s1;
        wd1[t] = d1;
    }
}

// ---- layer1 features: h1 (bf16), es1/ed1 (fp32) ----
__global__ void k_feat1(const float* __restrict__ x, const float* __restrict__ W1,
                        const float* __restrict__ ws1, const float* __restrict__ wd1,
                        unsigned short* __restrict__ h1, float* __restrict__ es1,
                        float* __restrict__ ed1, int n) {
    int node = blockIdx.x;
    int c = threadIdx.x;  // 0..127
    float xv[7];
#pragma unroll
    for (int k = 0; k < 7; k++) xv[k] = x[node * 7 + k];
    float acc = 0.f;
#pragma unroll
    for (int k = 0; k < 7; k++) acc += xv[k] * W1[k * 128 + c];
    h1[(size_t)node * 128 + c] = f2bf(acc);
    if (c < 2) {
        float s = 0.f;
#pragma unroll
        for (int k = 0; k < 7; k++) s += xv[k] * ws1[k * 2 + c];
        es1[node * 2 + c] = s;
    } else if (c < 4) {
        int h = c - 2;
        float s = 0.f;
#pragma unroll
        for (int k = 0; k < 7; k++) s += xv[k] * wd1[k * 2 + h];
        ed1[node * 2 + h] = s;
    }
}

// ---- GAT aggregation, one wave per dst node; h is bf16 ----
// LAYER==1: concat+b1+relu -> out[n][128] fp32; fused es2/ed2 epilogue.
// LAYER==2: mean+b2 -> fused classifier -> out[n][4] (final output).
template <int LAYER>
__global__ void k_aggr(const unsigned short* __restrict__ h, const float* __restrict__ es,
                       const float* __restrict__ ed, const int* __restrict__ rs,
                       const int* __restrict__ ssrc, const float* __restrict__ bias,
                       float* __restrict__ out, const float* __restrict__ ws2,
                       const float* __restrict__ wd2, float* __restrict__ es2,
                       float* __restrict__ ed2, const float* __restrict__ Wc1,
                       const float* __restrict__ bc1, const float* __restrict__ Wc2,
                       const float* __restrict__ bc2, int n) {
    int wid = threadIdx.x >> 6, lane = threadIdx.x & 63;
    int node = blockIdx.x * 4 + wid;
    if (node >= n) return;
    int beg = rs[node], deg = rs[node + 1] - beg;
    float2 edv = *(const float2*)&ed[node * 2];
    float2 esn = *(const float2*)&es[node * 2];
    float e0s = lrelu(esn.x + edv.x);  // implicit self-loop score
    float e1s = lrelu(esn.y + edv.y);
    int head = lane >> 5;
    float accx, accy;

    if (deg <= 64) {
        // ---- fast path: edge state register-resident ----
        bool valid = lane < deg;
        int sv = valid ? ssrc[beg + lane] : 0;
        float2 ev;
        ev.x = 0.f; ev.y = 0.f;
        if (valid) ev = *(const float2*)&es[sv * 2];
        float e0 = valid ? lrelu(ev.x + edv.x) : -3.0e38f;
        float e1 = valid ? lrelu(ev.y + edv.y) : -3.0e38f;
        float m0 = fmaxf(wave_red_max(e0), e0s);
        float m1 = fmaxf(wave_red_max(e1), e1s);
        float p0 = valid ? __expf(e0 - m0) : 0.f;
        float p1 = valid ? __expf(e1 - m1) : 0.f;
        float exs0 = __expf(e0s - m0), exs1 = __expf(e1s - m1);
        float inv0 = 1.f / (wave_red_sum(p0) + exs0);
        float inv1 = 1.f / (wave_red_sum(p1) + exs1);
        float a0 = p0 * inv0, a1 = p1 * inv1;
        float aself = head ? exs1 * inv1 : exs0 * inv0;
        ushort2 hvs = *(const ushort2*)&h[(size_t)node * 128 + lane * 2];
        float ax0 = bf2f(hvs.x) * aself, ay0 = bf2f(hvs.y) * aself;
        float ax1 = 0.f, ay1 = 0.f;
        int j = 0;
        for (; j + 8 <= deg; j += 8) {  // 8 gathers in flight, 2 acc pairs
            int sj[8];
            float aa[8];
#pragma unroll
            for (int q = 0; q < 8; q++) {
                sj[q] = __shfl(sv, j + q);
                // shuffle BOTH heads unconditionally, select after (R6 lesson)
                float b0 = __shfl(a0, j + q);
                float b1 = __shfl(a1, j + q);
                aa[q] = head ? b1 : b0;
            }
            ushort2 hg[8];
#pragma unroll
            for (int q = 0; q < 8; q++)
                hg[q] = *(const ushort2*)&h[(size_t)sj[q] * 128 + lane * 2];
#pragma unroll
            for (int q = 0; q < 8; q++) {
                float hx = bf2f(hg[q].x), hy = bf2f(hg[q].y);
                if (q & 1) { ax1 += hx * aa[q]; ay1 += hy * aa[q]; }
                else       { ax0 += hx * aa[q]; ay0 += hy * aa[q]; }
            }
        }
        for (; j < deg; j++) {
            int sj = __shfl(sv, j);
            float b0 = __shfl(a0, j), b1 = __shfl(a1, j);
            float aa = head ? b1 : b0;
            ushort2 hh = *(const ushort2*)&h[(size_t)sj * 128 + lane * 2];
            ax0 += bf2f(hh.x) * aa; ay0 += bf2f(hh.y) * aa;
        }
        accx = ax0 + ax1; accy = ay0 + ay1;
    } else {
        // ---- generic chunked path (deg > 64; vanishingly rare) ----
        float m0 = e0s, s0 = 1.f, m1 = e1s, s1 = 1.f;
        for (int c0 = 0; c0 < deg; c0 += 64) {
            int i = c0 + lane;
            bool val = i < deg;
            int sv = val ? ssrc[beg + i] : 0;
            float e0 = val ? lrelu(es[sv * 2 + 0] + edv.x) : -3.0e38f;
            float e1 = val ? lrelu(es[sv * 2 + 1] + edv.y) : -3.0e38f;
            float nm0 = fmaxf(m0, wave_red_max(e0));
            float nm1 = fmaxf(m1, wave_red_max(e1));
            float p0 = val ? __expf(e0 - nm0) : 0.f;
            float p1 = val ? __expf(e1 - nm1) : 0.f;
            s0 = s0 * __expf(m0 - nm0) + wave_red_sum(p0);
            s1 = s1 * __expf(m1 - nm1) + wave_red_sum(p1);
            m0 = nm0; m1 = nm1;
        }
        float inv0 = 1.f / s0, inv1 = 1.f / s1;
        float aself = head ? __expf(e1s - m1) * inv1 : __expf(e0s - m0) * inv0;
        ushort2 hvs = *(const ushort2*)&h[(size_t)node * 128 + lane * 2];
        accx = bf2f(hvs.x) * aself; accy = bf2f(hvs.y) * aself;
        for (int c0 = 0; c0 < deg; c0 += 64) {
            int i = c0 + lane;
            bool val = i < deg;
            int sv = val ? ssrc[beg + i] : 0;
            float a0 = 0.f, a1 = 0.f;
            if (val) {
                float e0 = lrelu(es[sv * 2 + 0] + edv.x);
                float e1 = lrelu(es[sv * 2 + 1] + edv.y);
                a0 = __expf(e0 - m0) * inv0;
                a1 = __expf(e1 - m1) * inv1;
            }
            int cnt = min(64, deg - c0);
            for (int j = 0; j < cnt; j++) {
                int sj = __shfl(sv, j);
                float b0 = __shfl(a0, j);
                float b1 = __shfl(a1, j);
                float a = head ? b1 : b0;
                ushort2 hh = *(const ushort2*)&h[(size_t)sj * 128 + lane * 2];
                accx += bf2f(hh.x) * a; accy += bf2f(hh.y) * a;
            }
        }
    }

    if (LAYER == 1) {
        float2 bv = *(const float2*)&bias[lane * 2];
        float ox = fmaxf(accx + bv.x, 0.f);
        float oy = fmaxf(accy + bv.y, 0.f);
        float2 o; o.x = ox; o.y = oy;
        *(float2*)&out[(size_t)node * 128 + lane * 2] = o;
        // fused es2/ed2: channel c0=2*lane, c1=2*lane+1; ws2/wd2 layout [k][h]
        float4 wsv = *(const float4*)&ws2[lane * 4];
        float4 wdv = *(const float4*)&wd2[lane * 4];
        float s0 = ox * wsv.x + oy * wsv.z;
        float s1 = ox * wsv.y + oy * wsv.w;
        float d0 = ox * wdv.x + oy * wdv.z;
        float d1 = ox * wdv.y + oy * wdv.w;
        s0 = wave_red_sum(s0); s1 = wave_red_sum(s1);
        d0 = wave_red_sum(d0); d1 = wave_red_sum(d1);
        if (lane == 0) {
            float2 sv2; sv2.x = s0; sv2.y = s1;
            float2 dv2; dv2.x = d0; dv2.y = d1;
            *(float2*)&es2[node * 2] = sv2;
            *(float2*)&ed2[node * 2] = dv2;
        }
    } else {
        // mean heads (+b2): lane l and l+32 both end up with channel pair 2*(l&31)
        float px = __shfl_xor(accx, 32);
        float py = __shfl_xor(accy, 32);
        int l2 = lane & 31;
        float2 bv = *(const float2*)&bias[l2 * 2];
        float ox = 0.5f * (accx + px) + bv.x;   // channel 2*l2
        float oy = 0.5f * (accy + py) + bv.y;   // channel 2*l2+1
        // fused classifier: y[c]=relu(sum_k o[k]*Wc1[k][c]+bc1[c]); out=y@Wc2+bc2
        float yc0 = bc1[lane], yc1 = 0.f;
#pragma unroll
        for (int q = 0; q < 32; q += 2) {
            float vx0 = __shfl(ox, q), vy0 = __shfl(oy, q);
            float vx1 = __shfl(ox, q + 1), vy1 = __shfl(oy, q + 1);
            yc0 += vx0 * Wc1[(2 * q) * 64 + lane] + vy0 * Wc1[(2 * q + 1) * 64 + lane];
            yc1 += vx1 * Wc1[(2 * q + 2) * 64 + lane] + vy1 * Wc1[(2 * q + 3) * 64 + lane];
        }
        float y = fmaxf(yc0 + yc1, 0.f);
        float4 w2v = *(const float4*)&Wc2[lane * 4];
        float p0 = y * w2v.x, p1 = y * w2v.y, p2 = y * w2v.z, p3 = y * w2v.w;
        p0 = wave_red_sum(p0); p1 = wave_red_sum(p1);
        p2 = wave_red_sum(p2); p3 = wave_red_sum(p3);
        if (lane == 0) {
            float4 o; o.x = p0 + bc2[0]; o.y = p1 + bc2[1];
            o.z = p2 + bc2[2]; o.w = p3 + bc2[3];
            *(float4*)&out[(size_t)node * 4] = o;
        }
    }
}

// ---- layer2 GEMM: h2[M,128] (bf16) = out1[M,128] (fp32) @ W2[128,128] ----
__global__ void k_gemm2(const float* __restrict__ A, const float* __restrict__ B,
                        unsigned short* __restrict__ C, int M) {
    __shared__ float As[32][65];
    __shared__ float Bs[32][132];
    int bm = blockIdx.x * 64;
    int t = threadIdx.x;
    int tx = t & 31;
    int ty = t >> 5;
    float acc[8][4];
#pragma unroll
    for (int i = 0; i < 8; i++)
#pragma unroll
        for (int j = 0; j < 4; j++) acc[i][j] = 0.f;

    for (int k0 = 0; k0 < 128; k0 += 32) {
        int lk = t & 31, lm = t >> 5;
#pragma unroll
        for (int p = 0; p < 8; p++) {
            int m = lm + p * 8;
            int row = bm + m;
            As[lk][m] = (row < M) ? A[(size_t)row * 128 + k0 + lk] : 0.f;
        }
        int bn = t & 127, bk = t >> 7;
#pragma unroll
        for (int p = 0; p < 16; p++) {
            Bs[bk + p * 2][bn] = B[(k0 + bk + p * 2) * 128 + bn];
        }
        __syncthreads();
#pragma unroll
        for (int k = 0; k < 32; k++) {
            float a[8];
#pragma unroll
            for (int i = 0; i < 8; i++) a[i] = As[k][ty * 8 + i];
            float4 bv = *(const float4*)&Bs[k][tx * 4];
            float b[4] = {bv.x, bv.y, bv.z, bv.w};
#pragma unroll
            for (int i = 0; i < 8; i++)
#pragma unroll
                for (int j = 0; j < 4; j++) acc[i][j] += a[i] * b[j];
        }
        __syncthreads();
    }
#pragma unroll
    for (int i = 0; i < 8; i++) {
        int row = bm + ty * 8 + i;
        if (row < M) {
            ushort4 v;
            v.x = f2bf(acc[i][0]); v.y = f2bf(acc[i][1]);
            v.z = f2bf(acc[i][2]); v.w = f2bf(acc[i][3]);
            *(ushort4*)&C[(size_t)row * 128 + tx * 4] = v;
        }
    }
}

extern "C" void kernel_launch(void* const* d_in, const int* in_sizes, int n_in,
                              void* d_out, int out_size, void* d_ws, size_t ws_size,
                              hipStream_t stream) {
    const float* x   = (const float*)d_in[0];
    const int*   ei  = (const int*)d_in[1];
    const float* W1  = (const float*)d_in[2];
    const float* as1 = (const float*)d_in[3];
    const float* ad1 = (const float*)d_in[4];
    const float* b1  = (const float*)d_in[5];
    const float* W2  = (const float*)d_in[6];
    const float* as2 = (const float*)d_in[7];
    const float* ad2 = (const float*)d_in[8];
    const float* b2  = (const float*)d_in[9];
    const float* Wc1 = (const float*)d_in[10];
    const float* bc1 = (const float*)d_in[11];
    const float* Wc2 = (const float*)d_in[12];
    const float* bc2 = (const float*)d_in[13];
    float* out = (float*)d_out;

    int n = in_sizes[0] / 7;
    int E = in_sizes[1] / 2;
    const int* srcA = ei;
    const int* dstA = ei + E;

    char* ws = (char*)d_ws;
    size_t off = 0;
    auto alloc = [&](size_t bytes) -> char* {
        char* p = ws + off;
        off += (bytes + 255) & ~(size_t)255;
        return p;
    };
    unsigned short* bufH = (unsigned short*)alloc((size_t)n * 128 * 2);  // h1 then h2 (bf16)
    float* bufO = (float*)alloc((size_t)n * 128 * 4);  // out1 (fp32)
    float* es1  = (float*)alloc((size_t)n * 2 * 4);
    float* ed1  = (float*)alloc((size_t)n * 2 * 4);
    float* es2  = (float*)alloc((size_t)n * 2 * 4);
    float* ed2  = (float*)alloc((size_t)n * 2 * 4);
    float* ws1  = (float*)alloc(64);
    float* wd1  = (float*)alloc(64);
    float* ws2v = (float*)alloc(256 * 4);
    float* wd2v = (float*)alloc(256 * 4);
    int* rs   = (int*)alloc((size_t)(n + 1) * 4);
    int* cnt  = (int*)alloc((size_t)n * 4);
    int* part = (int*)alloc(512 * 4);
    int* ssrc = (int*)alloc((size_t)E * 4);

    int eb = (E + 255) / 256;
    int nb = (n + 255) / 256;  // 391 (<512, fits k_scan2)

    hipMemsetAsync(cnt, 0, (size_t)n * 4, stream);
    k_hist<<<eb, 256, 0, stream>>>(dstA, cnt, E);
    k_scan1<<<nb, 256, 0, stream>>>(cnt, rs, part, n);
    k_scan2<<<1, 512, 0, stream>>>(part, nb);
    k_scan3<<<nb, 256, 0, stream>>>(rs, part, n, E);
    hipMemsetAsync(cnt, 0, (size_t)n * 4, stream);
    k_scatter<<<eb, 256, 0, stream>>>(srcA, dstA, rs, cnt, ssrc, E);

    k_prep<<<1, 256, 0, stream>>>(W1, as1, ad1, W2, as2, ad2, ws1, wd1, ws2v, wd2v);
    k_feat1<<<n, 128, 0, stream>>>(x, W1, ws1, wd1, bufH, es1, ed1, n);
    k_aggr<1><<<(n + 3) / 4, 256, 0, stream>>>(bufH, es1, ed1, rs, ssrc, b1, bufO,
                                               ws2v, wd2v, es2, ed2,
                                               nullptr, nullptr, nullptr, nullptr, n);
    k_gemm2<<<(n + 63) / 64, 256, 0, stream>>>(bufO, W2, bufH, n);
    k_aggr<2><<<(n + 3) / 4, 256, 0, stream>>>(bufH, es2, ed2, rs, ssrc, b2, out,
                                               nullptr, nullptr, nullptr, nullptr,
                                               Wc1, bc1, Wc2, bc2, n);
}

// Round 12
// 603.496 us; speedup vs baseline: 1.2937x; 1.0335x over previous
//
#include <hip/hip_runtime.h>
#include <hip/hip_bf16.h>

// GAT: N=100000 nodes, E=1.6M edges, IN=7, H=2 heads, C=64, NC=4.
// R11 post-mortem: aggr time invariant under 2x byte cut -> per-edge
// instruction/latency bound (3 shfl + 1 wave-wide load per edge).
// R12: 4 edges/wave-instruction: 4x16-lane groups, 8ch/lane via uint4 bf16
// load; per 4 edges = 3 shfl + 1 load. Cross-group xor-reduce once/node.

#define LRELU_SLOPE 0.2f

__device__ __forceinline__ float wave_red_max(float v) {
#pragma unroll
    for (int o = 32; o > 0; o >>= 1) v = fmaxf(v, __shfl_xor(v, o));
    return v;
}
__device__ __forceinline__ float wave_red_sum(float v) {
#pragma unroll
    for (int o = 32; o > 0; o >>= 1) v += __shfl_xor(v, o);
    return v;
}
__device__ __forceinline__ float lrelu(float v) { return v > 0.f ? v : LRELU_SLOPE * v; }
__device__ __forceinline__ unsigned short f2bf(float f) {  // RNE, finite inputs
    unsigned int x = __float_as_uint(f);
    return (unsigned short)((x + 0x7fffu + ((x >> 16) & 1u)) >> 16);
}
// accumulate 8 bf16 channels (packed in uint4) scaled by a into f[8]
__device__ __forceinline__ void fma8(float* f, uint4 hv, float a) {
    unsigned u[4] = {hv.x, hv.y, hv.z, hv.w};
#pragma unroll
    for (int i = 0; i < 4; i++) {
        float lo = __uint_as_float(u[i] << 16);
        float hi = __uint_as_float(u[i] & 0xffff0000u);
        f[2 * i]     += lo * a;
        f[2 * i + 1] += hi * a;
    }
}

// ---- CSR build ----
__global__ void k_hist(const int* __restrict__ dstA, int* __restrict__ cnt, int E) {
    int i = blockIdx.x * 256 + threadIdx.x;
    if (i < E) atomicAdd(&cnt[dstA[i]], 1);
}

__global__ void k_scan1(const int* __restrict__ cnt, int* __restrict__ rs,
                        int* __restrict__ part, int n) {
    __shared__ int sm[256];
    int t = threadIdx.x;
    int i = blockIdx.x * 256 + t;
    int v = (i < n) ? cnt[i] : 0;
    sm[t] = v;
    __syncthreads();
#pragma unroll
    for (int off = 1; off < 256; off <<= 1) {
        int x = (t >= off) ? sm[t - off] : 0;
        __syncthreads();
        sm[t] += x;
        __syncthreads();
    }
    if (i < n) rs[i] = sm[t] - v;
    if (t == 255) part[blockIdx.x] = sm[255];
}

__global__ void k_scan2(int* part, int np) {  // np <= 512
    __shared__ int sm[512];
    int t = threadIdx.x;
    int v = (t < np) ? part[t] : 0;
    sm[t] = v;
    __syncthreads();
#pragma unroll
    for (int off = 1; off < 512; off <<= 1) {
        int x = (t >= off) ? sm[t - off] : 0;
        __syncthreads();
        sm[t] += x;
        __syncthreads();
    }
    if (t < np) part[t] = sm[t] - v;
}

__global__ void k_scan3(int* rs, const int* __restrict__ part, int n, int total) {
    int i = blockIdx.x * 256 + threadIdx.x;
    if (i < n) rs[i] += part[blockIdx.x];
    if (i == 0) rs[n] = total;
}

__global__ void k_scatter(const int* __restrict__ srcA, const int* __restrict__ dstA,
                          const int* __restrict__ rs, int* __restrict__ cur,
                          int* __restrict__ ssrc, int E) {
    int i = blockIdx.x * 256 + threadIdx.x;
    if (i < E) {
        int d = dstA[i];
        int p = atomicAdd(&cur[d], 1);
        ssrc[rs[d] + p] = srcA[i];
    }
}

// ---- precompute ws/wd = W @ a ----
__global__ void k_prep(const float* __restrict__ W1, const float* __restrict__ as1,
                       const float* __restrict__ ad1, const float* __restrict__ W2,
                       const float* __restrict__ as2, const float* __restrict__ ad2,
                       float* __restrict__ ws1, float* __restrict__ wd1,
                       float* __restrict__ ws2, float* __restrict__ wd2) {
    int t = threadIdx.x;  // t = k*2+h for W2 (k<128, h<2)
    int k = t >> 1, h = t & 1;
    float s = 0.f, d = 0.f;
    for (int cc = 0; cc < 64; cc++) {
        float w = W2[k * 128 + h * 64 + cc];
        s += w * as2[h * 64 + cc];
        d += w * ad2[h * 64 + cc];
    }
    ws2[t] = s;
    wd2[t] = d;
    if (t < 14) {
        int kk = t >> 1, hh = t & 1;
        float s1 = 0.f, d1 = 0.f;
        for (int cc = 0; cc < 64; cc++) {
            float w = W1[kk * 128 + hh * 64 + cc];
            s1 += w * as1[hh * 64 + cc];
            d1 += w * ad1[hh * 64 + cc];
        }
        ws1[t] = s1;
        wd1[t] = d1;
    }
}

// ---- layer1 features: h1 (bf16), es1/ed1 (fp32) ----
__global__ void k_feat1(const float* __restrict__ x, const float* __restrict__ W1,
                        const float* __restrict__ ws1, const float* __restrict__ wd1,
                        unsigned short* __restrict__ h1, float* __restrict__ es1,
                        float* __restrict__ ed1, int n) {
    int node = blockIdx.x;
    int c = threadIdx.x;  // 0..127
    float xv[7];
#pragma unroll
    for (int k = 0; k < 7; k++) xv[k] = x[node * 7 + k];
    float acc = 0.f;
#pragma unroll
    for (int k = 0; k < 7; k++) acc += xv[k] * W1[k * 128 + c];
    h1[(size_t)node * 128 + c] = f2bf(acc);
    if (c < 2) {
        float s = 0.f;
#pragma unroll
        for (int k = 0; k < 7; k++) s += xv[k] * ws1[k * 2 + c];
        es1[node * 2 + c] = s;
    } else if (c < 4) {
        int h = c - 2;
        float s = 0.f;
#pragma unroll
        for (int k = 0; k < 7; k++) s += xv[k] * wd1[k * 2 + h];
        ed1[node * 2 + h] = s;
    }
}

// ---- GAT aggregation, one wave per dst node; h is bf16 ----
// Layout: 4 groups of 16 lanes; group g handles edge j+g; lane covers 8 ch
// (base = (lane&15)*8). Cross-group xor(16,32) reduce once at end.
// LAYER==1: concat+b1+relu -> out[n][128] fp32; fused es2/ed2 epilogue.
// LAYER==2: mean+b2 -> fused classifier -> out[n][4].
template <int LAYER>
__global__ void k_aggr(const unsigned short* __restrict__ h, const float* __restrict__ es,
                       const float* __restrict__ ed, const int* __restrict__ rs,
                       const int* __restrict__ ssrc, const float* __restrict__ bias,
                       float* __restrict__ out, const float* __restrict__ ws2,
                       const float* __restrict__ wd2, float* __restrict__ es2,
                       float* __restrict__ ed2, const float* __restrict__ Wc1,
                       const float* __restrict__ bc1, const float* __restrict__ Wc2,
                       const float* __restrict__ bc2, int n) {
    int wid = threadIdx.x >> 6, lane = threadIdx.x & 63;
    int node = blockIdx.x * 4 + wid;
    if (node >= n) return;
    int grp = lane >> 4, sub = lane & 15;
    int base = sub * 8;       // my channel base (0..120)
    int hd = sub >> 3;        // my channels' head (0: ch<64, 1: ch>=64)
    int beg = rs[node], deg = rs[node + 1] - beg;
    float2 edv = *(const float2*)&ed[node * 2];
    float2 esn = *(const float2*)&es[node * 2];
    float e0s = lrelu(esn.x + edv.x);  // implicit self-loop score
    float e1s = lrelu(esn.y + edv.y);
    float f[8] = {0.f, 0.f, 0.f, 0.f, 0.f, 0.f, 0.f, 0.f};

    if (deg <= 64) {
        // ---- phase 1: softmax stats, edge = lane (register-resident) ----
        bool valid = lane < deg;
        int sv = valid ? ssrc[beg + lane] : 0;
        float2 ev; ev.x = 0.f; ev.y = 0.f;
        if (valid) ev = *(const float2*)&es[sv * 2];
        float e0 = valid ? lrelu(ev.x + edv.x) : -3.0e38f;
        float e1 = valid ? lrelu(ev.y + edv.y) : -3.0e38f;
        float m0 = fmaxf(wave_red_max(e0), e0s);
        float m1 = fmaxf(wave_red_max(e1), e1s);
        float p0 = valid ? __expf(e0 - m0) : 0.f;   // invalid lanes -> a=0 (tail safety)
        float p1 = valid ? __expf(e1 - m1) : 0.f;
        float exs0 = __expf(e0s - m0), exs1 = __expf(e1s - m1);
        float inv0 = 1.f / (wave_red_sum(p0) + exs0);
        float inv1 = 1.f / (wave_red_sum(p1) + exs1);
        float a0 = p0 * inv0, a1 = p1 * inv1;
        // ---- self (group 0 only; counted once after cross-group reduce) ----
        if (grp == 0) {
            float aself = hd ? exs1 * inv1 : exs0 * inv0;
            uint4 hvs = *(const uint4*)&h[(size_t)node * 128 + base];
            fma8(f, hvs, aself);
        }
        // ---- phase 2: 4 edges per instruction slot, 2 slots deep ----
        int j = 0;
        for (; j + 8 <= deg; j += 8) {
            int jj0 = j + grp, jj1 = j + 4 + grp;
            int s0v = __shfl(sv, jj0), s1v = __shfl(sv, jj1);
            float b00 = __shfl(a0, jj0), b10 = __shfl(a1, jj0);
            float b01 = __shfl(a0, jj1), b11 = __shfl(a1, jj1);
            float av0 = hd ? b10 : b00;
            float av1 = hd ? b11 : b01;
            uint4 h0 = *(const uint4*)&h[(size_t)s0v * 128 + base];
            uint4 h1 = *(const uint4*)&h[(size_t)s1v * 128 + base];
            fma8(f, h0, av0);
            fma8(f, h1, av1);
        }
        for (; j < deg; j += 4) {  // tail: jj<=63 always; a auto-0 past deg
            int jj = j + grp;
            int sjv = __shfl(sv, jj);
            float b0 = __shfl(a0, jj), b1 = __shfl(a1, jj);
            float av = hd ? b1 : b0;
            uint4 hv = *(const uint4*)&h[(size_t)sjv * 128 + base];
            fma8(f, hv, av);
        }
    } else {
        // ---- generic chunked path (deg > 64; essentially never at mean 16) ----
        float m0 = e0s, s0 = 1.f, m1 = e1s, s1 = 1.f;
        for (int c0 = 0; c0 < deg; c0 += 64) {
            int i = c0 + lane;
            bool val = i < deg;
            int sv = val ? ssrc[beg + i] : 0;
            float e0 = val ? lrelu(es[sv * 2 + 0] + edv.x) : -3.0e38f;
            float e1 = val ? lrelu(es[sv * 2 + 1] + edv.y) : -3.0e38f;
            float nm0 = fmaxf(m0, wave_red_max(e0));
            float nm1 = fmaxf(m1, wave_red_max(e1));
            float p0 = val ? __expf(e0 - nm0) : 0.f;
            float p1 = val ? __expf(e1 - nm1) : 0.f;
            s0 = s0 * __expf(m0 - nm0) + wave_red_sum(p0);
            s1 = s1 * __expf(m1 - nm1) + wave_red_sum(p1);
            m0 = nm0; m1 = nm1;
        }
        float inv0 = 1.f / s0, inv1 = 1.f / s1;
        if (grp == 0) {
            float aself = hd ? __expf(e1s - m1) * inv1 : __expf(e0s - m0) * inv0;
            uint4 hvs = *(const uint4*)&h[(size_t)node * 128 + base];
            fma8(f, hvs, aself);
        }
        for (int c0 = 0; c0 < deg; c0 += 64) {
            int i = c0 + lane;
            bool val = i < deg;
            int svc = val ? ssrc[beg + i] : 0;
            float a0c = 0.f, a1c = 0.f;
            if (val) {
                float e0 = lrelu(es[svc * 2 + 0] + edv.x);
                float e1 = lrelu(es[svc * 2 + 1] + edv.y);
                a0c = __expf(e0 - m0) * inv0;
                a1c = __expf(e1 - m1) * inv1;
            }
            int cnt = min(64, deg - c0);
            for (int jl = 0; jl < cnt; jl += 4) {
                int jj = jl + grp;  // <=63; lanes past cnt have a=0
                int sjv = __shfl(svc, jj);
                float b0 = __shfl(a0c, jj), b1 = __shfl(a1c, jj);
                float av = hd ? b1 : b0;
                uint4 hv = *(const uint4*)&h[(size_t)sjv * 128 + base];
                fma8(f, hv, av);
            }
        }
    }

    // ---- cross-group reduction: all lanes end with totals for their 8 ch ----
#pragma unroll
    for (int r = 0; r < 8; r++) {
        f[r] += __shfl_xor(f[r], 16);
        f[r] += __shfl_xor(f[r], 32);
    }

    if (LAYER == 1) {
        float o[8];
#pragma unroll
        for (int r = 0; r < 8; r++) o[r] = fmaxf(f[r] + bias[base + r], 0.f);
        if (grp == 0) {
            float4 v0 = {o[0], o[1], o[2], o[3]};
            float4 v1 = {o[4], o[5], o[6], o[7]};
            *(float4*)&out[(size_t)node * 128 + base] = v0;
            *(float4*)&out[(size_t)node * 128 + base + 4] = v1;
        }
        // fused es2/ed2 (ws2/wd2 layout [k][h]); 4 group-copies -> x0.25
        float s0 = 0.f, s1 = 0.f, d0 = 0.f, d1 = 0.f;
#pragma unroll
        for (int r = 0; r < 8; r++) {
            float2 wsv = *(const float2*)&ws2[(base + r) * 2];
            float2 wdv = *(const float2*)&wd2[(base + r) * 2];
            s0 += o[r] * wsv.x; s1 += o[r] * wsv.y;
            d0 += o[r] * wdv.x; d1 += o[r] * wdv.y;
        }
        s0 = wave_red_sum(s0) * 0.25f;
        s1 = wave_red_sum(s1) * 0.25f;
        d0 = wave_red_sum(d0) * 0.25f;
        d1 = wave_red_sum(d1) * 0.25f;
        if (lane == 0) {
            float2 sv2; sv2.x = s0; sv2.y = s1;
            float2 dv2; dv2.x = d0; dv2.y = d1;
            *(float2*)&es2[node * 2] = sv2;
            *(float2*)&ed2[node * 2] = dv2;
        }
    } else {
        // mean heads + b2: partner channels (base^64) live at lane sub^8
        float p[8];
#pragma unroll
        for (int r = 0; r < 8; r++) p[r] = __shfl_xor(f[r], 8);
        float o2[8];
#pragma unroll
        for (int r = 0; r < 8; r++)
            o2[r] = 0.5f * (f[r] + p[r]) + bias[(base & 63) + r];  // valid on sub<8
        // classifier: y[lane] = relu(sum_k o2[k]*Wc1[k][lane] + bc1[lane])
        float yc = bc1[lane];
#pragma unroll
        for (int k = 0; k < 64; k++) {
            float ov = __shfl(o2[k & 7], k >> 3);  // src lanes 0..7 (valid o2)
            yc += ov * Wc1[k * 64 + lane];
        }
        float y = fmaxf(yc, 0.f);
        float4 w2v = *(const float4*)&Wc2[lane * 4];
        float p0 = y * w2v.x, p1 = y * w2v.y, p2 = y * w2v.z, p3 = y * w2v.w;
        p0 = wave_red_sum(p0); p1 = wave_red_sum(p1);
        p2 = wave_red_sum(p2); p3 = wave_red_sum(p3);
        if (lane == 0) {
            float4 o; o.x = p0 + bc2[0]; o.y = p1 + bc2[1];
            o.z = p2 + bc2[2]; o.w = p3 + bc2[3];
            *(float4*)&out[(size_t)node * 4] = o;
        }
    }
}

// ---- layer2 GEMM: h2[M,128] (bf16) = out1[M,128] (fp32) @ W2[128,128] ----
__global__ void k_gemm2(const float* __restrict__ A, const float* __restrict__ B,
                        unsigned short* __restrict__ C, int M) {
    __shared__ float As[32][65];
    __shared__ float Bs[32][132];
    int bm = blockIdx.x * 64;
    int t = threadIdx.x;
    int tx = t & 31;
    int ty = t >> 5;
    float acc[8][4];
#pragma unroll
    for (int i = 0; i < 8; i++)
#pragma unroll
        for (int j = 0; j < 4; j++) acc[i][j] = 0.f;

    for (int k0 = 0; k0 < 128; k0 += 32) {
        int lk = t & 31, lm = t >> 5;
#pragma unroll
        for (int p = 0; p < 8; p++) {
            int m = lm + p * 8;
            int row = bm + m;
            As[lk][m] = (row < M) ? A[(size_t)row * 128 + k0 + lk] : 0.f;
        }
        int bn = t & 127, bk = t >> 7;
#pragma unroll
        for (int p = 0; p < 16; p++) {
            Bs[bk + p * 2][bn] = B[(k0 + bk + p * 2) * 128 + bn];
        }
        __syncthreads();
#pragma unroll
        for (int k = 0; k < 32; k++) {
            float a[8];
#pragma unroll
            for (int i = 0; i < 8; i++) a[i] = As[k][ty * 8 + i];
            float4 bv = *(const float4*)&Bs[k][tx * 4];
            float b[4] = {bv.x, bv.y, bv.z, bv.w};
#pragma unroll
            for (int i = 0; i < 8; i++)
#pragma unroll
                for (int j = 0; j < 4; j++) acc[i][j] += a[i] * b[j];
        }
        __syncthreads();
    }
#pragma unroll
    for (int i = 0; i < 8; i++) {
        int row = bm + ty * 8 + i;
        if (row < M) {
            ushort4 v;
            v.x = f2bf(acc[i][0]); v.y = f2bf(acc[i][1]);
            v.z = f2bf(acc[i][2]); v.w = f2bf(acc[i][3]);
            *(ushort4*)&C[(size_t)row * 128 + tx * 4] = v;
        }
    }
}

extern "C" void kernel_launch(void* const* d_in, const int* in_sizes, int n_in,
                              void* d_out, int out_size, void* d_ws, size_t ws_size,
                              hipStream_t stream) {
    const float* x   = (const float*)d_in[0];
    const int*   ei  = (const int*)d_in[1];
    const float* W1  = (const float*)d_in[2];
    const float* as1 = (const float*)d_in[3];
    const float* ad1 = (const float*)d_in[4];
    const float* b1  = (const float*)d_in[5];
    const float* W2  = (const float*)d_in[6];
    const float* as2 = (const float*)d_in[7];
    const float* ad2 = (const float*)d_in[8];
    const float* b2  = (const float*)d_in[9];
    const float* Wc1 = (const float*)d_in[10];
    const float* bc1 = (const float*)d_in[11];
    const float* Wc2 = (const float*)d_in[12];
    const float* bc2 = (const float*)d_in[13];
    float* out = (float*)d_out;

    int n = in_sizes[0] / 7;
    int E = in_sizes[1] / 2;
    const int* srcA = ei;
    const int* dstA = ei + E;

    char* ws = (char*)d_ws;
    size_t off = 0;
    auto alloc = [&](size_t bytes) -> char* {
        char* p = ws + off;
        off += (bytes + 255) & ~(size_t)255;
        return p;
    };
    unsigned short* bufH = (unsigned short*)alloc((size_t)n * 128 * 2);  // h1 then h2 (bf16)
    float* bufO = (float*)alloc((size_t)n * 128 * 4);  // out1 (fp32)
    float* es1  = (float*)alloc((size_t)n * 2 * 4);
    float* ed1  = (float*)alloc((size_t)n * 2 * 4);
    float* es2  = (float*)alloc((size_t)n * 2 * 4);
    float* ed2  = (float*)alloc((size_t)n * 2 * 4);
    float* ws1  = (float*)alloc(64);
    float* wd1  = (float*)alloc(64);
    float* ws2v = (float*)alloc(256 * 4);
    float* wd2v = (float*)alloc(256 * 4);
    int* rs   = (int*)alloc((size_t)(n + 1) * 4);
    int* cnt  = (int*)alloc((size_t)n * 4);
    int* part = (int*)alloc(512 * 4);
    int* ssrc = (int*)alloc((size_t)E * 4);

    int eb = (E + 255) / 256;
    int nb = (n + 255) / 256;  // 391 (<512, fits k_scan2)

    hipMemsetAsync(cnt, 0, (size_t)n * 4, stream);
    k_hist<<<eb, 256, 0, stream>>>(dstA, cnt, E);
    k_scan1<<<nb, 256, 0, stream>>>(cnt, rs, part, n);
    k_scan2<<<1, 512, 0, stream>>>(part, nb);
    k_scan3<<<nb, 256, 0, stream>>>(rs, part, n, E);
    hipMemsetAsync(cnt, 0, (size_t)n * 4, stream);
    k_scatter<<<eb, 256, 0, stream>>>(srcA, dstA, rs, cnt, ssrc, E);

    k_prep<<<1, 256, 0, stream>>>(W1, as1, ad1, W2, as2, ad2, ws1, wd1, ws2v, wd2v);
    k_feat1<<<n, 128, 0, stream>>>(x, W1, ws1, wd1, bufH, es1, ed1, n);
    k_aggr<1><<<(n + 3) / 4, 256, 0, stream>>>(bufH, es1, ed1, rs, ssrc, b1, bufO,
                                               ws2v, wd2v, es2, ed2,
                                               nullptr, nullptr, nullptr, nullptr, n);
    k_gemm2<<<(n + 63) / 64, 256, 0, stream>>>(bufO, W2, bufH, n);
    k_aggr<2><<<(n + 3) / 4, 256, 0, stream>>>(bufH, es2, ed2, rs, ssrc, b2, out,
                                               nullptr, nullptr, nullptr, nullptr,
                                               Wc1, bc1, Wc2, bc2, n);
}